// Round 2
// baseline (1129.109 us; speedup 1.0000x reference)
//
#include <hip/hip_runtime.h>
#include <hip/hip_bf16.h>

#define BATCH 4
#define CCH   256
#define HH    128
#define WW    128
#define HWSZ  (HH * WW)         // 16384
#define NHEADS 4
#define DHEAD 64

// ---------------------------------------------------------------------------
// GEMM: Y[z,o,p] = sum_c W[o,c] * X[z,c,p]
// 128x128 tile, BK=16, 256 threads, 8x8 per thread as 2x2 blocks of float4.
// xbs/ybs: per-blockIdx.z element strides (0 when z-dim is 1).
// ---------------------------------------------------------------------------
__global__ __launch_bounds__(256) void gemm_wx(
    const float* __restrict__ W, const float* __restrict__ X,
    float* __restrict__ Y, int O, int C, int P,
    long long xbs, long long ybs)
{
    constexpr int BM = 128, BN = 128, BK = 16;
    __shared__ float As[BK][BM + 4];   // As[k][m]
    __shared__ float Bs[BK][BN + 4];   // Bs[k][n]

    const float* Xb = X + (size_t)blockIdx.z * xbs;
    float*       Yb = Y + (size_t)blockIdx.z * ybs;

    const int o0 = blockIdx.y * BM;
    const int p0 = blockIdx.x * BN;
    const int tid = threadIdx.x;
    const int tx = tid & 15;       // p dir
    const int ty = tid >> 4;       // o dir

    float acc[2][2][4][4] = {};

    for (int c0 = 0; c0 < C; c0 += BK) {
        // A tile: 128 rows x 16 cols of W, stored transposed As[k][m]
        #pragma unroll
        for (int l = 0; l < 2; ++l) {
            const int idx = tid + l * 256;
            const int row = idx >> 2;     // 0..127
            const int c4  = idx & 3;      // 0..3 (groups of 4 cols)
            const float4 wv = *reinterpret_cast<const float4*>(
                &W[(size_t)(o0 + row) * C + c0 + c4 * 4]);
            As[c4 * 4 + 0][row] = wv.x;
            As[c4 * 4 + 1][row] = wv.y;
            As[c4 * 4 + 2][row] = wv.z;
            As[c4 * 4 + 3][row] = wv.w;
        }
        // B tile: 16 rows x 128 cols of X
        #pragma unroll
        for (int l = 0; l < 2; ++l) {
            const int idx = tid + l * 256;
            const int row  = idx >> 5;    // 0..15
            const int col4 = idx & 31;    // 0..31
            *reinterpret_cast<float4*>(&Bs[row][col4 * 4]) =
                *reinterpret_cast<const float4*>(
                    &Xb[(size_t)(c0 + row) * P + p0 + col4 * 4]);
        }
        __syncthreads();

        #pragma unroll
        for (int kk = 0; kk < BK; ++kk) {
            const float4 a0 = *reinterpret_cast<const float4*>(&As[kk][ty * 4]);
            const float4 a1 = *reinterpret_cast<const float4*>(&As[kk][ty * 4 + 64]);
            const float4 b0 = *reinterpret_cast<const float4*>(&Bs[kk][tx * 4]);
            const float4 b1 = *reinterpret_cast<const float4*>(&Bs[kk][tx * 4 + 64]);
            const float av[2][4] = {{a0.x, a0.y, a0.z, a0.w}, {a1.x, a1.y, a1.z, a1.w}};
            const float bv[2][4] = {{b0.x, b0.y, b0.z, b0.w}, {b1.x, b1.y, b1.z, b1.w}};
            #pragma unroll
            for (int im = 0; im < 2; ++im)
                #pragma unroll
                for (int jn = 0; jn < 2; ++jn)
                    #pragma unroll
                    for (int i = 0; i < 4; ++i)
                        #pragma unroll
                        for (int j = 0; j < 4; ++j)
                            acc[im][jn][i][j] += av[im][i] * bv[jn][j];
        }
        __syncthreads();
    }

    #pragma unroll
    for (int im = 0; im < 2; ++im)
        #pragma unroll
        for (int i = 0; i < 4; ++i) {
            const int row = o0 + im * 64 + ty * 4 + i;
            #pragma unroll
            for (int jn = 0; jn < 2; ++jn) {
                float4 o;
                o.x = acc[im][jn][i][0];
                o.y = acc[im][jn][i][1];
                o.z = acc[im][jn][i][2];
                o.w = acc[im][jn][i][3];
                *reinterpret_cast<float4*>(
                    &Yb[(size_t)row * P + p0 + jn * 64 + tx * 4]) = o;
            }
        }
}

// ---------------------------------------------------------------------------
// Dilated neighborhood attention. qkv region layout: [768][H][W] per batch
// (q ch 0..255, k 256..511, v 512..767); head hi uses d-slice hi*64..
// Rate r = hi+1. OOB neighbors: score 0 participates in softmax; v contrib 0.
// qbs/ybs: per-blockIdx.z element strides (0 when z-dim is 1).
// ---------------------------------------------------------------------------
__global__ __launch_bounds__(256) void attn_kernel(
    const float* __restrict__ qkv, float* __restrict__ yatt,
    long long qbs, long long ybs)
{
    const int hi = blockIdx.y;
    const int p  = blockIdx.x * 256 + threadIdx.x;   // 0..16383
    const int yy = p >> 7;
    const int xx = p & 127;
    const int r  = hi + 1;

    const float* base = qkv + (size_t)blockIdx.z * qbs;
    const float* q = base + (size_t)(hi * DHEAD) * HWSZ;
    const float* k = base + (size_t)(CCH + hi * DHEAD) * HWSZ;
    const float* v = base + (size_t)(2 * CCH + hi * DHEAD) * HWSZ;

    float qreg[DHEAD];
    #pragma unroll
    for (int d = 0; d < DHEAD; ++d) qreg[d] = q[(size_t)d * HWSZ + p];

    float sc[9];
    #pragma unroll
    for (int n = 0; n < 9; ++n) {
        const int dy = (n / 3 - 1) * r;
        const int dx = (n % 3 - 1) * r;
        const int y2 = yy + dy, x2 = xx + dx;
        float s = 0.f;
        if (y2 >= 0 && y2 < HH && x2 >= 0 && x2 < WW) {
            const int p2 = y2 * WW + x2;
            #pragma unroll 8
            for (int d = 0; d < DHEAD; ++d)
                s += qreg[d] * k[(size_t)d * HWSZ + p2];
        }
        sc[n] = s;
    }

    float m = sc[0];
    #pragma unroll
    for (int n = 1; n < 9; ++n) m = fmaxf(m, sc[n]);
    float wgt[9], den = 0.f;
    #pragma unroll
    for (int n = 0; n < 9; ++n) { wgt[n] = __expf(sc[n] - m); den += wgt[n]; }
    const float inv = 1.f / den;
    #pragma unroll
    for (int n = 0; n < 9; ++n) wgt[n] *= inv;

    float* out = yatt + (size_t)blockIdx.z * ybs + (size_t)(hi * DHEAD) * HWSZ;
    for (int d = 0; d < DHEAD; ++d) {
        float acc = 0.f;
        #pragma unroll
        for (int n = 0; n < 9; ++n) {
            const int dy = (n / 3 - 1) * r;
            const int dx = (n % 3 - 1) * r;
            const int y2 = yy + dy, x2 = xx + dx;
            if (y2 >= 0 && y2 < HH && x2 >= 0 && x2 < WW)
                acc += wgt[n] * v[(size_t)d * HWSZ + y2 * WW + x2];
        }
        out[(size_t)d * HWSZ + p] = acc;
    }
}

// ---------------------------------------------------------------------------
// BN stats over full y [BATCH][CCH][HWSZ]: stats[c]=mean, stats[256+c]=invstd
// ---------------------------------------------------------------------------
__global__ __launch_bounds__(256) void bn_stats(
    const float* __restrict__ y, float* __restrict__ stats)
{
    const int c = blockIdx.x;
    const int tid = threadIdx.x;
    float s = 0.f, s2 = 0.f;
    for (int b = 0; b < BATCH; ++b) {
        const float4* pc = reinterpret_cast<const float4*>(
            y + ((size_t)b * CCH + c) * HWSZ);
        for (int i = tid; i < HWSZ / 4; i += 256) {
            const float4 val = pc[i];
            s  += val.x + val.y + val.z + val.w;
            s2 += val.x * val.x + val.y * val.y + val.z * val.z + val.w * val.w;
        }
    }
    __shared__ float sh0[256], sh1[256];
    sh0[tid] = s; sh1[tid] = s2;
    __syncthreads();
    for (int st = 128; st > 0; st >>= 1) {
        if (tid < st) { sh0[tid] += sh0[tid + st]; sh1[tid] += sh1[tid + st]; }
        __syncthreads();
    }
    if (tid == 0) {
        const float N = (float)(BATCH * HWSZ);
        const float mean = sh0[0] / N;
        const float var  = sh1[0] / N - mean * mean;
        stats[c]       = mean;
        stats[CCH + c] = rsqrtf(var + 1e-5f);
    }
}

// ---------------------------------------------------------------------------
// In-place epilogue: y = x + silu( (y - mean) * invstd * gamma + beta )
// One float4 per thread.
// ---------------------------------------------------------------------------
__global__ __launch_bounds__(256) void bn_silu_res(
    float* __restrict__ y, const float* __restrict__ x,
    const float* __restrict__ stats, const float* __restrict__ gamma,
    const float* __restrict__ beta)
{
    const size_t i4 = (size_t)blockIdx.x * 256 + threadIdx.x;
    const size_t i  = i4 * 4;
    const int c = (int)((i >> 14) & 255);
    const float mean = stats[c];
    const float inv  = stats[CCH + c];
    const float g = gamma[c], bt = beta[c];

    float4 yv = *reinterpret_cast<float4*>(&(((float*)y)[i]));
    const float4 xv = *reinterpret_cast<const float4*>(&x[i]);
    float vin[4] = {yv.x, yv.y, yv.z, yv.w};
    const float xin[4] = {xv.x, xv.y, xv.z, xv.w};
    float vo[4];
    #pragma unroll
    for (int t = 0; t < 4; ++t) {
        const float yn = (vin[t] - mean) * inv * g + bt;
        const float sig = 1.f / (1.f + __expf(-yn));
        vo[t] = xin[t] + yn * sig;
    }
    yv.x = vo[0]; yv.y = vo[1]; yv.z = vo[2]; yv.w = vo[3];
    *reinterpret_cast<float4*>(&(((float*)y)[i])) = yv;
}

// ---------------------------------------------------------------------------
extern "C" void kernel_launch(void* const* d_in, const int* in_sizes, int n_in,
                              void* d_out, int out_size, void* d_ws, size_t ws_size,
                              hipStream_t stream)
{
    const float* x      = (const float*)d_in[0];
    const float* w_qkv  = (const float*)d_in[1];
    const float* w_proj = (const float*)d_in[2];
    const float* gamma  = (const float*)d_in[3];
    const float* beta   = (const float*)d_in[4];
    float* out = (float*)d_out;   // doubles as yproj scratch, then final output

    float* ws    = (float*)d_ws;
    float* stats = ws;            // 512 floats, aliases dead qkv region later

    const size_t qkv_b  = (size_t)3 * CCH * HWSZ;   // per-batch qkv elems
    const size_t yatt_b = (size_t)CCH * HWSZ;       // per-batch yatt elems

    const size_t need_full = ((size_t)BATCH * qkv_b + (size_t)BATCH * yatt_b) * 4
                             + 512 * 4;

    if (ws_size >= need_full) {
        // Full-batch path: qkv [4][768][HWSZ], yatt [4][256][HWSZ]
        float* qkv  = ws;
        float* yatt = ws + (size_t)BATCH * qkv_b;

        dim3 g1(HWSZ / 128, 768 / 128, BATCH);
        gemm_wx<<<g1, 256, 0, stream>>>(w_qkv, x, qkv, 768, CCH, HWSZ,
                                        (long long)CCH * HWSZ, (long long)qkv_b);
        dim3 g2(HWSZ / 256, NHEADS, BATCH);
        attn_kernel<<<g2, 256, 0, stream>>>(qkv, yatt,
                                            (long long)qkv_b, (long long)yatt_b);
        dim3 g3(HWSZ / 128, CCH / 128, BATCH);
        gemm_wx<<<g3, 256, 0, stream>>>(w_proj, yatt, out, CCH, CCH, HWSZ,
                                        (long long)yatt_b, (long long)yatt_b);
    } else {
        // Per-batch path: ws = qkv_b (48 MB) + yatt_b (16 MB) = 64 MB exactly
        float* qkv  = ws;
        float* yatt = ws + qkv_b;
        for (int b = 0; b < BATCH; ++b) {
            const float* xb = x + (size_t)b * CCH * HWSZ;
            dim3 g1(HWSZ / 128, 768 / 128, 1);
            gemm_wx<<<g1, 256, 0, stream>>>(w_qkv, xb, qkv, 768, CCH, HWSZ, 0, 0);
            dim3 g2(HWSZ / 256, NHEADS, 1);
            attn_kernel<<<g2, 256, 0, stream>>>(qkv, yatt, 0, 0);
            dim3 g3(HWSZ / 128, CCH / 128, 1);
            gemm_wx<<<g3, 256, 0, stream>>>(w_proj, yatt,
                                            out + (size_t)b * yatt_b,
                                            CCH, CCH, HWSZ, 0, 0);
        }
    }

    // BN statistics over out [4][256][HWSZ] (stats aliases dead qkv region)
    bn_stats<<<CCH, 256, 0, stream>>>(out, stats);

    // In-place BN + SiLU + residual
    bn_silu_res<<<(size_t)BATCH * CCH * HWSZ / 4 / 256, 256, 0, stream>>>(
        out, x, stats, gamma, beta);
}

// Round 3
// 519.943 us; speedup vs baseline: 2.1716x; 2.1716x over previous
//
#include <hip/hip_runtime.h>
#include <hip/hip_bf16.h>

#define BATCH 4
#define CCH   256
#define HH    128
#define WW    128
#define HWSZ  (HH * WW)         // 16384
#define NHEADS 4
#define DHEAD 64

typedef unsigned short u16;

__device__ __forceinline__ float bf2f(u16 u) {
    return __uint_as_float(((unsigned)u) << 16);
}
__device__ __forceinline__ u16 f2bf(float f) {
    unsigned u = __float_as_uint(f);
    unsigned r = (u + 0x7fffu + ((u >> 16) & 1u)) >> 16;
    return (u16)r;
}

// ---------------------------------------------------------------------------
// GEMM: Y[z,o,p] = sum_c W[o,c] * X[z,c,p]
// W fp32 row-major (O x C). X fp32 or bf16. Y fp32 or bf16.
// 128x128 tile, BK=16, 256 threads, 8x8 per thread as 2x2 float4 blocks.
// ---------------------------------------------------------------------------
template <int XBF, int YBF>
__global__ __launch_bounds__(256) void gemm_wx(
    const float* __restrict__ W, const void* __restrict__ Xv,
    void* __restrict__ Yv, int C, int P,
    long long xbs, long long ybs)
{
    constexpr int BM = 128, BN = 128, BK = 16;
    __shared__ float As[BK][BM + 4];
    __shared__ float Bs[BK][BN + 4];

    const int o0 = blockIdx.y * BM;
    const int p0 = blockIdx.x * BN;
    const int tid = threadIdx.x;
    const int tx = tid & 15;
    const int ty = tid >> 4;

    float acc[2][2][4][4] = {};

    for (int c0 = 0; c0 < C; c0 += BK) {
        // A tile: W[o0+row][c0 + c4*4 .. +3] -> As[k][m]
        #pragma unroll
        for (int l = 0; l < 2; ++l) {
            const int idx = tid + l * 256;
            const int row = idx >> 2;
            const int c4  = idx & 3;
            const float4 wv = *reinterpret_cast<const float4*>(
                &W[(size_t)(o0 + row) * C + c0 + c4 * 4]);
            As[c4 * 4 + 0][row] = wv.x;
            As[c4 * 4 + 1][row] = wv.y;
            As[c4 * 4 + 2][row] = wv.z;
            As[c4 * 4 + 3][row] = wv.w;
        }
        // B tile: X[c0+row][p0 + col4*4 .. +3]
        #pragma unroll
        for (int l = 0; l < 2; ++l) {
            const int idx = tid + l * 256;
            const int row  = idx >> 5;
            const int col4 = idx & 31;
            float4 f;
            if (XBF) {
                const u16* Xb = (const u16*)Xv + (size_t)blockIdx.z * xbs;
                const ushort4 t = *reinterpret_cast<const ushort4*>(
                    &Xb[(size_t)(c0 + row) * P + p0 + col4 * 4]);
                f.x = bf2f(t.x); f.y = bf2f(t.y); f.z = bf2f(t.z); f.w = bf2f(t.w);
            } else {
                const float* Xb = (const float*)Xv + (size_t)blockIdx.z * xbs;
                f = *reinterpret_cast<const float4*>(
                    &Xb[(size_t)(c0 + row) * P + p0 + col4 * 4]);
            }
            *reinterpret_cast<float4*>(&Bs[row][col4 * 4]) = f;
        }
        __syncthreads();

        #pragma unroll
        for (int kk = 0; kk < BK; ++kk) {
            const float4 a0 = *reinterpret_cast<const float4*>(&As[kk][ty * 4]);
            const float4 a1 = *reinterpret_cast<const float4*>(&As[kk][ty * 4 + 64]);
            const float4 b0 = *reinterpret_cast<const float4*>(&Bs[kk][tx * 4]);
            const float4 b1 = *reinterpret_cast<const float4*>(&Bs[kk][tx * 4 + 64]);
            const float av[2][4] = {{a0.x, a0.y, a0.z, a0.w}, {a1.x, a1.y, a1.z, a1.w}};
            const float bv[2][4] = {{b0.x, b0.y, b0.z, b0.w}, {b1.x, b1.y, b1.z, b1.w}};
            #pragma unroll
            for (int im = 0; im < 2; ++im)
                #pragma unroll
                for (int jn = 0; jn < 2; ++jn)
                    #pragma unroll
                    for (int i = 0; i < 4; ++i)
                        #pragma unroll
                        for (int j = 0; j < 4; ++j)
                            acc[im][jn][i][j] += av[im][i] * bv[jn][j];
        }
        __syncthreads();
    }

    #pragma unroll
    for (int im = 0; im < 2; ++im)
        #pragma unroll
        for (int i = 0; i < 4; ++i) {
            const int row = o0 + im * 64 + ty * 4 + i;
            #pragma unroll
            for (int jn = 0; jn < 2; ++jn) {
                const int col = p0 + jn * 64 + tx * 4;
                if (YBF) {
                    u16* Yb = (u16*)Yv + (size_t)blockIdx.z * ybs;
                    ushort4 o;
                    o.x = f2bf(acc[im][jn][i][0]);
                    o.y = f2bf(acc[im][jn][i][1]);
                    o.z = f2bf(acc[im][jn][i][2]);
                    o.w = f2bf(acc[im][jn][i][3]);
                    *reinterpret_cast<ushort4*>(&Yb[(size_t)row * P + col]) = o;
                } else {
                    float* Yb = (float*)Yv + (size_t)blockIdx.z * ybs;
                    float4 o;
                    o.x = acc[im][jn][i][0];
                    o.y = acc[im][jn][i][1];
                    o.z = acc[im][jn][i][2];
                    o.w = acc[im][jn][i][3];
                    *reinterpret_cast<float4*>(&Yb[(size_t)row * P + col]) = o;
                }
            }
        }
}

// ---------------------------------------------------------------------------
// Dilated neighborhood attention on bf16 qkv ([768][H][W] per batch image;
// q ch 0..255, k 256..511, v 512..767; head hi -> d-slice hi*64..).
// Rate r = hi+1. OOB neighbor: score exactly 0 (still in softmax), v contrib 0.
// d-chunked accumulation: no big register arrays, no spill.
// ---------------------------------------------------------------------------
__global__ __launch_bounds__(256) void attn_kernel(
    const u16* __restrict__ qkv, u16* __restrict__ yatt,
    long long qbs, long long ybs)
{
    const int hi = blockIdx.y;
    const int p  = blockIdx.x * 256 + threadIdx.x;
    const int yy = p >> 7;
    const int xx = p & 127;
    const int r  = hi + 1;

    const u16* base = qkv + (size_t)blockIdx.z * qbs;
    const u16* q = base + (size_t)(hi * DHEAD) * HWSZ;
    const u16* k = base + (size_t)(CCH + hi * DHEAD) * HWSZ;
    const u16* v = base + (size_t)(2 * CCH + hi * DHEAD) * HWSZ;

    // Clamped neighbor offsets + validity masks
    int offs[9];
    float valid[9];
    #pragma unroll
    for (int n = 0; n < 9; ++n) {
        const int dy = (n / 3 - 1) * r;
        const int dx = (n % 3 - 1) * r;
        const int y2 = yy + dy, x2 = xx + dx;
        const bool ok = (y2 >= 0) && (y2 < HH) && (x2 >= 0) && (x2 < WW);
        valid[n] = ok ? 1.f : 0.f;
        const int y2c = min(max(y2, 0), HH - 1);
        const int x2c = min(max(x2, 0), WW - 1);
        offs[n] = y2c * WW + x2c;
    }

    // Scores: d-chunked (8 q values live at a time)
    float sc[9] = {};
    for (int d0 = 0; d0 < DHEAD; d0 += 8) {
        float qv[8];
        #pragma unroll
        for (int dd = 0; dd < 8; ++dd)
            qv[dd] = bf2f(q[(size_t)(d0 + dd) * HWSZ + p]);
        #pragma unroll
        for (int dd = 0; dd < 8; ++dd) {
            const u16* kd = k + (size_t)(d0 + dd) * HWSZ;
            #pragma unroll
            for (int n = 0; n < 9; ++n)
                sc[n] += qv[dd] * bf2f(kd[offs[n]]);
        }
    }
    #pragma unroll
    for (int n = 0; n < 9; ++n) sc[n] *= valid[n];   // OOB -> exactly 0

    // Softmax over 9 (invalid entries participate with score 0, per reference)
    float m = sc[0];
    #pragma unroll
    for (int n = 1; n < 9; ++n) m = fmaxf(m, sc[n]);
    float wgt[9], den = 0.f;
    #pragma unroll
    for (int n = 0; n < 9; ++n) { wgt[n] = __expf(sc[n] - m); den += wgt[n]; }
    const float inv = 1.f / den;
    #pragma unroll
    for (int n = 0; n < 9; ++n) wgt[n] *= inv * valid[n];  // mask for PV

    // PV
    u16* outp = yatt + (size_t)blockIdx.z * ybs + (size_t)(hi * DHEAD) * HWSZ;
    for (int d0 = 0; d0 < DHEAD; d0 += 4) {
        #pragma unroll
        for (int dd = 0; dd < 4; ++dd) {
            const u16* vd = v + (size_t)(d0 + dd) * HWSZ;
            float acc = 0.f;
            #pragma unroll
            for (int n = 0; n < 9; ++n)
                acc += wgt[n] * bf2f(vd[offs[n]]);
            outp[(size_t)(d0 + dd) * HWSZ + p] = f2bf(acc);
        }
    }
}

// ---------------------------------------------------------------------------
// BN stats over y [BATCH][CCH][HWSZ] fp32: stats[c]=mean, stats[256+c]=invstd
// ---------------------------------------------------------------------------
__global__ __launch_bounds__(256) void bn_stats(
    const float* __restrict__ y, float* __restrict__ stats)
{
    const int c = blockIdx.x;
    const int tid = threadIdx.x;
    float s = 0.f, s2 = 0.f;
    for (int b = 0; b < BATCH; ++b) {
        const float4* pc = reinterpret_cast<const float4*>(
            y + ((size_t)b * CCH + c) * HWSZ);
        for (int i = tid; i < HWSZ / 4; i += 256) {
            const float4 val = pc[i];
            s  += val.x + val.y + val.z + val.w;
            s2 += val.x * val.x + val.y * val.y + val.z * val.z + val.w * val.w;
        }
    }
    __shared__ float sh0[256], sh1[256];
    sh0[tid] = s; sh1[tid] = s2;
    __syncthreads();
    for (int st = 128; st > 0; st >>= 1) {
        if (tid < st) { sh0[tid] += sh0[tid + st]; sh1[tid] += sh1[tid + st]; }
        __syncthreads();
    }
    if (tid == 0) {
        const float N = (float)(BATCH * HWSZ);
        const float mean = sh0[0] / N;
        const float var  = sh1[0] / N - mean * mean;
        stats[c]       = mean;
        stats[CCH + c] = rsqrtf(var + 1e-5f);
    }
}

// ---------------------------------------------------------------------------
// In-place epilogue: y = x + silu( (y - mean) * invstd * gamma + beta )
// ---------------------------------------------------------------------------
__global__ __launch_bounds__(256) void bn_silu_res(
    float* __restrict__ y, const float* __restrict__ x,
    const float* __restrict__ stats, const float* __restrict__ gamma,
    const float* __restrict__ beta)
{
    const size_t i = ((size_t)blockIdx.x * 256 + threadIdx.x) * 4;
    const int c = (int)((i >> 14) & 255);
    const float mean = stats[c];
    const float inv  = stats[CCH + c];
    const float g = gamma[c], bt = beta[c];

    float4 yv = *reinterpret_cast<float4*>(&y[i]);
    const float4 xv = *reinterpret_cast<const float4*>(&x[i]);
    float vin[4] = {yv.x, yv.y, yv.z, yv.w};
    const float xin[4] = {xv.x, xv.y, xv.z, xv.w};
    float vo[4];
    #pragma unroll
    for (int t = 0; t < 4; ++t) {
        const float yn = (vin[t] - mean) * inv * g + bt;
        const float sig = 1.f / (1.f + __expf(-yn));
        vo[t] = xin[t] + yn * sig;
    }
    yv.x = vo[0]; yv.y = vo[1]; yv.z = vo[2]; yv.w = vo[3];
    *reinterpret_cast<float4*>(&y[i]) = yv;
}

// ---------------------------------------------------------------------------
extern "C" void kernel_launch(void* const* d_in, const int* in_sizes, int n_in,
                              void* d_out, int out_size, void* d_ws, size_t ws_size,
                              hipStream_t stream)
{
    const float* x      = (const float*)d_in[0];
    const float* w_qkv  = (const float*)d_in[1];
    const float* w_proj = (const float*)d_in[2];
    const float* gamma  = (const float*)d_in[3];
    const float* beta   = (const float*)d_in[4];
    float* out = (float*)d_out;   // proj scratch, then final output (in place)

    const size_t qkv_e  = (size_t)3 * CCH * HWSZ;   // per-batch qkv elems
    const size_t yatt_e = (size_t)CCH * HWSZ;       // per-batch yatt elems

    const size_t need_full =
        ((size_t)BATCH * qkv_e + (size_t)BATCH * yatt_e) * sizeof(u16)
        + 512 * sizeof(float);   // ~128 MB + 2 KB

    u16* qkv  = (u16*)d_ws;
    float* stats;

    if (ws_size >= need_full) {
        // Full-batch: qkv bf16 [4][768][HWSZ], yatt bf16 [4][256][HWSZ]
        u16* yatt = qkv + (size_t)BATCH * qkv_e;
        stats = (float*)(yatt + (size_t)BATCH * yatt_e);

        dim3 g1(HWSZ / 128, 768 / 128, BATCH);
        gemm_wx<0, 1><<<g1, 256, 0, stream>>>(
            w_qkv, x, qkv, CCH, HWSZ,
            (long long)CCH * HWSZ, (long long)qkv_e);

        dim3 g2(HWSZ / 256, NHEADS, BATCH);
        attn_kernel<<<g2, 256, 0, stream>>>(
            qkv, yatt, (long long)qkv_e, (long long)yatt_e);

        dim3 g3(HWSZ / 128, CCH / 128, BATCH);
        gemm_wx<1, 0><<<g3, 256, 0, stream>>>(
            w_proj, yatt, out, CCH, HWSZ,
            (long long)yatt_e, (long long)yatt_e);
    } else {
        // Per-batch: qkv bf16 (24 MB) + yatt bf16 (8 MB) + stats
        u16* yatt = qkv + qkv_e;
        stats = (float*)(yatt + yatt_e);
        for (int b = 0; b < BATCH; ++b) {
            const float* xb = x + (size_t)b * CCH * HWSZ;
            dim3 g1(HWSZ / 128, 768 / 128, 1);
            gemm_wx<0, 1><<<g1, 256, 0, stream>>>(
                w_qkv, xb, qkv, CCH, HWSZ, 0, 0);
            dim3 g2(HWSZ / 256, NHEADS, 1);
            attn_kernel<<<g2, 256, 0, stream>>>(qkv, yatt, 0, 0);
            dim3 g3(HWSZ / 128, CCH / 128, 1);
            gemm_wx<1, 0><<<g3, 256, 0, stream>>>(
                w_proj, yatt, out + (size_t)b * yatt_e, CCH, HWSZ, 0, 0);
        }
    }

    // BN statistics + fused epilogue (in place on d_out)
    bn_stats<<<CCH, 256, 0, stream>>>(out, stats);
    bn_silu_res<<<(unsigned)((size_t)BATCH * CCH * HWSZ / 4 / 256), 256, 0, stream>>>(
        out, x, stats, gamma, beta);
}

// Round 4
// 254.504 us; speedup vs baseline: 4.4365x; 2.0430x over previous
//
#include <hip/hip_runtime.h>
#include <hip/hip_bf16.h>

#define BATCH 4
#define CCH   256
#define HH    128
#define WW    128
#define HWSZ  (HH * WW)         // 16384
#define NHEADS 4
#define DHEAD 64
#define KDIM  256
#define PDIM  16384

typedef unsigned short u16;
typedef short bf16x8 __attribute__((ext_vector_type(8)));
typedef float f32x4  __attribute__((ext_vector_type(4)));

__device__ __forceinline__ float bf2f(u16 u) {
    return __uint_as_float(((unsigned)u) << 16);
}
__device__ __forceinline__ u16 f2bf(float f) {
    unsigned u = __float_as_uint(f);
    unsigned r = (u + 0x7fffu + ((u >> 16) & 1u)) >> 16;
    return (u16)r;
}
__device__ __forceinline__ unsigned pack2(float a, float b) {
    return (unsigned)f2bf(a) | ((unsigned)f2bf(b) << 16);
}
__device__ __forceinline__ void gl_lds16(const u16* g, u16* l) {
    __builtin_amdgcn_global_load_lds(
        (const __attribute__((address_space(1))) void*)g,
        (__attribute__((address_space(3))) void*)l, 16, 0, 0);
}

// ---------------------------------------------------------------------------
// Weight fp32 -> bf16 conversion (both weights in one kernel).
// ---------------------------------------------------------------------------
__global__ __launch_bounds__(256) void wconv(
    const float* __restrict__ wq, const float* __restrict__ wp,
    u16* __restrict__ wqb, u16* __restrict__ wpb)
{
    const int i = (blockIdx.x * 256 + threadIdx.x) * 4;   // < 262144
    const float4 v = (i < 196608)
        ? *reinterpret_cast<const float4*>(&wq[i])
        : *reinterpret_cast<const float4*>(&wp[i - 196608]);
    ushort4 o;
    o.x = f2bf(v.x); o.y = f2bf(v.y); o.z = f2bf(v.z); o.w = f2bf(v.w);
    if (i < 196608) *reinterpret_cast<ushort4*>(&wqb[i]) = o;
    else            *reinterpret_cast<ushort4*>(&wpb[i - 196608]) = o;
}

// ---------------------------------------------------------------------------
// Transpose + convert: x [b][c][p] fp32 -> XT [b][p][c] bf16. 32x32 tiles.
// ---------------------------------------------------------------------------
__global__ __launch_bounds__(256) void transpose_x(
    const float* __restrict__ x, u16* __restrict__ XT)
{
    __shared__ float t[32][33];
    const int b  = blockIdx.z;
    const int c0 = blockIdx.y * 32;
    const int p0 = blockIdx.x * 32;
    const int tid = threadIdx.x;

    #pragma unroll
    for (int it = 0; it < 4; ++it) {
        const int r = it * 8 + (tid >> 5);
        const int col = tid & 31;
        t[r][col] = x[((size_t)b * CCH + c0 + r) * HWSZ + p0 + col];
    }
    __syncthreads();
    #pragma unroll
    for (int it = 0; it < 2; ++it) {
        const int prow = it * 16 + (tid >> 4);
        const int cpair = (tid & 15) * 2;
        const float v0 = t[cpair][prow];
        const float v1 = t[cpair + 1][prow];
        ushort2 o; o.x = f2bf(v0); o.y = f2bf(v1);
        *reinterpret_cast<ushort2*>(
            &XT[((size_t)b * HWSZ + p0 + prow) * CCH + c0 + cpair]) = o;
    }
}

// ---------------------------------------------------------------------------
// MFMA GEMM: D[o][p] = sum_k A[o][k] * B[p][k]   (both bf16, k-contiguous)
// A: [Orows][256]. B: [16384][256] (+ z*b_zs). K=256, BK=64, tile 128x128.
// 256 threads = 4 waves (2x2), each wave 64x64 via 16 x mfma 16x16x32.
// LDS rows 128B with XOR swizzle slot^=(row&7); staged via global_load_lds
// width 16 with pre-swizzled global source (linear LDS dest).
// OUT_FP32=0: Y bf16 [p][Ostride] (+z*y_zs). OUT_FP32=1: Y fp32 [o][P] (+z*y_zs).
// ---------------------------------------------------------------------------
template <int OUT_FP32>
__global__ __launch_bounds__(256) void gemm_mfma(
    const u16* __restrict__ A, const u16* __restrict__ B,
    void* __restrict__ Y, int Ostride, long long b_zs, long long y_zs)
{
    constexpr int BK = 64;
    __shared__ u16 As[128 * BK];
    __shared__ u16 Bs[128 * BK];

    const int tid  = threadIdx.x;
    const int lane = tid & 63;
    const int w    = tid >> 6;
    const int wm   = w >> 1, wn = w & 1;
    const int o0   = blockIdx.y * 128;
    const int p0   = blockIdx.x * 128;
    const u16* Bz  = B + (size_t)blockIdx.z * b_zs;

    // staging geometry: chunk q covers LDS rows q*8..q*8+7 (1 KB); lane i ->
    // row q*8 + (i>>3), slot i&7; source k-slot = (i&7) ^ (row&7).
    const int srow  = lane >> 3;
    const int sslot = (lane & 7) ^ srow;

    auto stage = [&](int c0) {
        #pragma unroll
        for (int j = 0; j < 4; ++j) {
            const int q = w * 4 + j;
            const int r = q * 8 + srow;
            gl_lds16(A  + (size_t)(o0 + r) * KDIM + c0 + sslot * 8, As + q * 512);
            gl_lds16(Bz + (size_t)(p0 + r) * KDIM + c0 + sslot * 8, Bs + q * 512);
        }
    };

    f32x4 acc[4][4];
    #pragma unroll
    for (int m = 0; m < 4; ++m)
        #pragma unroll
        for (int n = 0; n < 4; ++n)
            acc[m][n] = (f32x4){0.f, 0.f, 0.f, 0.f};

    stage(0);
    #pragma unroll
    for (int kt = 0; kt < KDIM / BK; ++kt) {
        __syncthreads();                      // drains gload_lds + LDS writes
        #pragma unroll
        for (int h = 0; h < 2; ++h) {
            bf16x8 af[4], bf[4];
            #pragma unroll
            for (int m = 0; m < 4; ++m) {
                const int r  = wm * 64 + m * 16 + (lane & 15);
                const int sl = ((h << 2) | (lane >> 4)) ^ (r & 7);
                af[m] = *reinterpret_cast<const bf16x8*>(As + r * BK + sl * 8);
            }
            #pragma unroll
            for (int n = 0; n < 4; ++n) {
                const int r  = wn * 64 + n * 16 + (lane & 15);
                const int sl = ((h << 2) | (lane >> 4)) ^ (r & 7);
                bf[n] = *reinterpret_cast<const bf16x8*>(Bs + r * BK + sl * 8);
            }
            #pragma unroll
            for (int m = 0; m < 4; ++m)
                #pragma unroll
                for (int n = 0; n < 4; ++n)
                    acc[m][n] = __builtin_amdgcn_mfma_f32_16x16x32_bf16(
                        af[m], bf[n], acc[m][n], 0, 0, 0);
        }
        if (kt + 1 < KDIM / BK) {
            __syncthreads();
            stage((kt + 1) * BK);
        }
    }

    const int g = lane >> 4, ln15 = lane & 15;
    if (OUT_FP32) {
        float* Yz = (float*)Y + (size_t)blockIdx.z * y_zs;
        #pragma unroll
        for (int m = 0; m < 4; ++m) {
            const int ow = o0 + wm * 64 + m * 16 + g * 4;
            #pragma unroll
            for (int n = 0; n < 4; ++n) {
                const int pc = p0 + wn * 64 + n * 16 + ln15;
                #pragma unroll
                for (int j = 0; j < 4; ++j)
                    Yz[(size_t)(ow + j) * PDIM + pc] = acc[m][n][j];
            }
        }
    } else {
        u16* Yz = (u16*)Y + (size_t)blockIdx.z * y_zs;
        #pragma unroll
        for (int m = 0; m < 4; ++m) {
            const int ow = o0 + wm * 64 + m * 16 + g * 4;
            #pragma unroll
            for (int n = 0; n < 4; ++n) {
                const int pc = p0 + wn * 64 + n * 16 + ln15;
                ushort4 st;
                st.x = f2bf(acc[m][n][0]);
                st.y = f2bf(acc[m][n][1]);
                st.z = f2bf(acc[m][n][2]);
                st.w = f2bf(acc[m][n][3]);
                *reinterpret_cast<ushort4*>(
                    &Yz[(size_t)pc * Ostride + ow]) = st;
            }
        }
    }
}

// ---------------------------------------------------------------------------
// Dilated neighborhood attention on QKVT [z][p][768] bf16 (q 0..255,
// k 256..511, v 512..767; head hi -> slice hi*64). Writes YT [z][p][256].
// Rate r = hi+1. OOB: score exactly 0 in softmax, zero v contribution.
// ---------------------------------------------------------------------------
__global__ __launch_bounds__(256) void attn2(
    const u16* __restrict__ QKVT, u16* __restrict__ YT)
{
    const int hi = blockIdx.y;
    const int p  = blockIdx.x * 256 + threadIdx.x;
    const int yy = p >> 7;
    const int xx = p & 127;
    const int r  = hi + 1;
    const size_t zbase = (size_t)blockIdx.z * HWSZ;

    // q -> registers (unpacked fp32)
    const uint4* qp = reinterpret_cast<const uint4*>(
        QKVT + (zbase + p) * 768 + hi * DHEAD);
    float qf[DHEAD];
    #pragma unroll
    for (int c4 = 0; c4 < 8; ++c4) {
        const uint4 t = qp[c4];
        const unsigned wv[4] = {t.x, t.y, t.z, t.w};
        #pragma unroll
        for (int d = 0; d < 4; ++d) {
            qf[c4 * 8 + d * 2 + 0] = __uint_as_float(wv[d] << 16);
            qf[c4 * 8 + d * 2 + 1] = __uint_as_float(wv[d] & 0xffff0000u);
        }
    }

    int   offs[9];
    float valid[9];
    #pragma unroll
    for (int n = 0; n < 9; ++n) {
        const int dy = (n / 3 - 1) * r;
        const int dx = (n % 3 - 1) * r;
        const int y2 = yy + dy, x2 = xx + dx;
        const bool ok = (y2 >= 0) && (y2 < HH) && (x2 >= 0) && (x2 < WW);
        valid[n] = ok ? 1.f : 0.f;
        const int y2c = min(max(y2, 0), HH - 1);
        const int x2c = min(max(x2, 0), WW - 1);
        offs[n] = y2c * WW + x2c;
    }

    float sc[9];
    #pragma unroll
    for (int n = 0; n < 9; ++n) {
        const uint4* kp = reinterpret_cast<const uint4*>(
            QKVT + (zbase + offs[n]) * 768 + CCH + hi * DHEAD);
        float s = 0.f;
        #pragma unroll
        for (int c4 = 0; c4 < 8; ++c4) {
            const uint4 t = kp[c4];
            const unsigned wv[4] = {t.x, t.y, t.z, t.w};
            #pragma unroll
            for (int d = 0; d < 4; ++d) {
                s += qf[c4 * 8 + d * 2 + 0] * __uint_as_float(wv[d] << 16);
                s += qf[c4 * 8 + d * 2 + 1] * __uint_as_float(wv[d] & 0xffff0000u);
            }
        }
        sc[n] = s * valid[n];
    }

    float m = sc[0];
    #pragma unroll
    for (int n = 1; n < 9; ++n) m = fmaxf(m, sc[n]);
    float wgt[9], den = 0.f;
    #pragma unroll
    for (int n = 0; n < 9; ++n) { wgt[n] = __expf(sc[n] - m); den += wgt[n]; }
    const float inv = 1.f / den;
    #pragma unroll
    for (int n = 0; n < 9; ++n) wgt[n] *= inv * valid[n];

    u16* outp = YT + (zbase + p) * CCH + hi * DHEAD;
    #pragma unroll
    for (int c4 = 0; c4 < 8; ++c4) {
        float a8[8] = {0.f, 0.f, 0.f, 0.f, 0.f, 0.f, 0.f, 0.f};
        #pragma unroll
        for (int n = 0; n < 9; ++n) {
            const uint4* vp = reinterpret_cast<const uint4*>(
                QKVT + (zbase + offs[n]) * 768 + 2 * CCH + hi * DHEAD);
            const uint4 t = vp[c4];
            const unsigned wv[4] = {t.x, t.y, t.z, t.w};
            #pragma unroll
            for (int d = 0; d < 4; ++d) {
                a8[d * 2 + 0] += wgt[n] * __uint_as_float(wv[d] << 16);
                a8[d * 2 + 1] += wgt[n] * __uint_as_float(wv[d] & 0xffff0000u);
            }
        }
        uint4 st;
        st.x = pack2(a8[0], a8[1]);
        st.y = pack2(a8[2], a8[3]);
        st.z = pack2(a8[4], a8[5]);
        st.w = pack2(a8[6], a8[7]);
        *reinterpret_cast<uint4*>(outp + c4 * 8) = st;
    }
}

// ---------------------------------------------------------------------------
// BN stage 1: partial (sum, sumsq) per (channel, chunk) over b and p-range.
// Deterministic tree reduction. part[(c*8+chunk)*2 + {0,1}].
// ---------------------------------------------------------------------------
__global__ __launch_bounds__(256) void bn_partial(
    const float* __restrict__ y, float* __restrict__ part)
{
    const int c = blockIdx.x;
    const int chunk = blockIdx.y;
    const int tid = threadIdx.x;
    float s = 0.f, s2 = 0.f;
    for (int b = 0; b < BATCH; ++b) {
        const float4* pc = reinterpret_cast<const float4*>(
            y + ((size_t)b * CCH + c) * HWSZ + chunk * 2048);
        for (int i = tid; i < 512; i += 256) {
            const float4 v = pc[i];
            s  += v.x + v.y + v.z + v.w;
            s2 += v.x * v.x + v.y * v.y + v.z * v.z + v.w * v.w;
        }
    }
    __shared__ float sh0[256], sh1[256];
    sh0[tid] = s; sh1[tid] = s2;
    __syncthreads();
    for (int st = 128; st > 0; st >>= 1) {
        if (tid < st) { sh0[tid] += sh0[tid + st]; sh1[tid] += sh1[tid + st]; }
        __syncthreads();
    }
    if (tid == 0) {
        part[(c * 8 + chunk) * 2 + 0] = sh0[0];
        part[(c * 8 + chunk) * 2 + 1] = sh1[0];
    }
}

__global__ __launch_bounds__(256) void bn_final(
    const float* __restrict__ part, float* __restrict__ stats)
{
    const int c = threadIdx.x;
    float s = 0.f, s2 = 0.f;
    #pragma unroll
    for (int j = 0; j < 8; ++j) {
        s  += part[(c * 8 + j) * 2 + 0];
        s2 += part[(c * 8 + j) * 2 + 1];
    }
    const float N = (float)(BATCH * HWSZ);
    const float mean = s / N;
    const float var  = s2 / N - mean * mean;
    stats[c]       = mean;
    stats[CCH + c] = rsqrtf(var + 1e-5f);
}

// ---------------------------------------------------------------------------
// In-place epilogue: y = x + silu( (y - mean) * invstd * gamma + beta )
// ---------------------------------------------------------------------------
__global__ __launch_bounds__(256) void bn_silu_res(
    float* __restrict__ y, const float* __restrict__ x,
    const float* __restrict__ stats, const float* __restrict__ gamma,
    const float* __restrict__ beta)
{
    const size_t i = ((size_t)blockIdx.x * 256 + threadIdx.x) * 4;
    const int c = (int)((i >> 14) & 255);
    const float mean = stats[c];
    const float inv  = stats[CCH + c];
    const float g = gamma[c], bt = beta[c];

    float4 yv = *reinterpret_cast<float4*>(&y[i]);
    const float4 xv = *reinterpret_cast<const float4*>(&x[i]);
    const float vin[4] = {yv.x, yv.y, yv.z, yv.w};
    const float xin[4] = {xv.x, xv.y, xv.z, xv.w};
    float vo[4];
    #pragma unroll
    for (int t = 0; t < 4; ++t) {
        const float yn = (vin[t] - mean) * inv * g + bt;
        const float sig = 1.f / (1.f + __expf(-yn));
        vo[t] = xin[t] + yn * sig;
    }
    yv.x = vo[0]; yv.y = vo[1]; yv.z = vo[2]; yv.w = vo[3];
    *reinterpret_cast<float4*>(&y[i]) = yv;
}

// ---------------------------------------------------------------------------
extern "C" void kernel_launch(void* const* d_in, const int* in_sizes, int n_in,
                              void* d_out, int out_size, void* d_ws, size_t ws_size,
                              hipStream_t stream)
{
    const float* x      = (const float*)d_in[0];
    const float* w_qkv  = (const float*)d_in[1];
    const float* w_proj = (const float*)d_in[2];
    const float* gamma  = (const float*)d_in[3];
    const float* beta   = (const float*)d_in[4];
    float* out = (float*)d_out;

    // ws layout (101.2 MB total; round-3 evidence: ws >= 134.2 MB):
    u16*   XT    = (u16*)d_ws;                       // [4][16384][256] bf16
    u16*   WQb   = XT + (size_t)BATCH * HWSZ * CCH;  // [768][256]
    u16*   WPb   = WQb + 768 * CCH;                  // [256][256]
    float* part  = (float*)(WPb + CCH * CCH);        // [256][8][2]
    float* stats = part + 4096;                      // [512]
    u16*   QKVT2 = (u16*)(stats + 512);              // [2][16384][768]
    u16*   YT2   = QKVT2 + (size_t)2 * HWSZ * 768;   // [2][16384][256]

    // 1) weights -> bf16
    wconv<<<256, 256, 0, stream>>>(w_qkv, w_proj, WQb, WPb);

    // 2) x -> XT (transpose + bf16)
    transpose_x<<<dim3(HWSZ / 32, CCH / 32, BATCH), 256, 0, stream>>>(x, XT);

    // 3) per batch-pair: QKV GEMM -> attention -> proj GEMM
    for (int pair = 0; pair < 2; ++pair) {
        const u16* Bx = XT + (size_t)pair * 2 * HWSZ * CCH;
        gemm_mfma<0><<<dim3(PDIM / 128, 768 / 128, 2), 256, 0, stream>>>(
            WQb, Bx, QKVT2, 768,
            (long long)HWSZ * CCH, (long long)HWSZ * 768);

        attn2<<<dim3(HWSZ / 256, NHEADS, 2), 256, 0, stream>>>(QKVT2, YT2);

        gemm_mfma<1><<<dim3(PDIM / 128, CCH / 128, 2), 256, 0, stream>>>(
            WPb, YT2, out + (size_t)pair * 2 * CCH * HWSZ, 0,
            (long long)HWSZ * CCH, (long long)CCH * HWSZ);
    }

    // 4) BN stats (two-stage, deterministic)
    bn_partial<<<dim3(CCH, 8), 256, 0, stream>>>(out, part);
    bn_final<<<1, 256, 0, stream>>>(part, stats);

    // 5) BN + SiLU + residual (in place on d_out)
    bn_silu_res<<<(unsigned)((size_t)BATCH * CCH * HWSZ / 4 / 256), 256, 0, stream>>>(
        out, x, stats, gamma, beta);
}

// Round 5
// 192.098 us; speedup vs baseline: 5.8778x; 1.3249x over previous
//
#include <hip/hip_runtime.h>
#include <hip/hip_bf16.h>

#define BATCH 4
#define CCH   256
#define HH    128
#define WW    128
#define HWSZ  (HH * WW)         // 16384
#define NHEADS 4
#define DHEAD 64
#define KDIM  256
#define PDIM  16384

typedef unsigned short u16;
typedef short bf16x8 __attribute__((ext_vector_type(8)));
typedef float f32x4  __attribute__((ext_vector_type(4)));

__device__ __forceinline__ float bf2f(u16 u) {
    return __uint_as_float(((unsigned)u) << 16);
}
__device__ __forceinline__ u16 f2bf(float f) {
    unsigned u = __float_as_uint(f);
    unsigned r = (u + 0x7fffu + ((u >> 16) & 1u)) >> 16;
    return (u16)r;
}
__device__ __forceinline__ unsigned pack2(float a, float b) {
    return (unsigned)f2bf(a) | ((unsigned)f2bf(b) << 16);
}
__device__ __forceinline__ void gl_lds16(const u16* g, u16* l) {
    __builtin_amdgcn_global_load_lds(
        (const __attribute__((address_space(1))) void*)g,
        (__attribute__((address_space(3))) void*)l, 16, 0, 0);
}

// ---------------------------------------------------------------------------
// Weight fp32 -> bf16 conversion (both weights in one kernel).
// ---------------------------------------------------------------------------
__global__ __launch_bounds__(256) void wconv(
    const float* __restrict__ wq, const float* __restrict__ wp,
    u16* __restrict__ wqb, u16* __restrict__ wpb)
{
    const int i = (blockIdx.x * 256 + threadIdx.x) * 4;   // < 262144
    const float4 v = (i < 196608)
        ? *reinterpret_cast<const float4*>(&wq[i])
        : *reinterpret_cast<const float4*>(&wp[i - 196608]);
    ushort4 o;
    o.x = f2bf(v.x); o.y = f2bf(v.y); o.z = f2bf(v.z); o.w = f2bf(v.w);
    if (i < 196608) *reinterpret_cast<ushort4*>(&wqb[i]) = o;
    else            *reinterpret_cast<ushort4*>(&wpb[i - 196608]) = o;
}

// ---------------------------------------------------------------------------
// Transpose + convert: x [b][c][p] fp32 -> XT [b][p][c] bf16. 32x32 tiles.
// ---------------------------------------------------------------------------
__global__ __launch_bounds__(256) void transpose_x(
    const float* __restrict__ x, u16* __restrict__ XT)
{
    __shared__ float t[32][33];
    const int b  = blockIdx.z;
    const int c0 = blockIdx.y * 32;
    const int p0 = blockIdx.x * 32;
    const int tid = threadIdx.x;

    #pragma unroll
    for (int it = 0; it < 4; ++it) {
        const int r = it * 8 + (tid >> 5);
        const int col = tid & 31;
        t[r][col] = x[((size_t)b * CCH + c0 + r) * HWSZ + p0 + col];
    }
    __syncthreads();
    #pragma unroll
    for (int it = 0; it < 2; ++it) {
        const int prow = it * 16 + (tid >> 4);
        const int cpair = (tid & 15) * 2;
        const float v0 = t[cpair][prow];
        const float v1 = t[cpair + 1][prow];
        ushort2 o; o.x = f2bf(v0); o.y = f2bf(v1);
        *reinterpret_cast<ushort2*>(
            &XT[((size_t)b * HWSZ + p0 + prow) * CCH + c0 + cpair]) = o;
    }
}

// ---------------------------------------------------------------------------
// MFMA GEMM: D[o][p] = sum_k A[o][k] * B[p][k]   (both bf16, k-contiguous)
// A: [Orows][256]. B: [16384][256] (+ z*b_zs). K=256, BK=64, tile 128x128.
// 256 threads = 4 waves (2x2), each wave 64x64 via 16 x mfma 16x16x32.
// LDS rows 128B with XOR swizzle slot^=(row&7); staged via global_load_lds
// width 16 with pre-swizzled global source (linear LDS dest).
// OUT_MODE=0: bf16 QKVH layout [(z*4+head)][p][q64|k64|v64] (O=768).
// OUT_MODE=1: fp32 [o][PDIM] (+ z*y_zs).
// ---------------------------------------------------------------------------
template <int OUT_MODE>
__global__ __launch_bounds__(256) void gemm_mfma(
    const u16* __restrict__ A, const u16* __restrict__ B,
    void* __restrict__ Y, long long b_zs, long long y_zs)
{
    constexpr int BK = 64;
    __shared__ u16 As[128 * BK];
    __shared__ u16 Bs[128 * BK];

    const int tid  = threadIdx.x;
    const int lane = tid & 63;
    const int w    = tid >> 6;
    const int wm   = w >> 1, wn = w & 1;
    const int o0   = blockIdx.y * 128;
    const int p0   = blockIdx.x * 128;
    const u16* Bz  = B + (size_t)blockIdx.z * b_zs;

    const int srow  = lane >> 3;
    const int sslot = (lane & 7) ^ srow;

    auto stage = [&](int c0) {
        #pragma unroll
        for (int j = 0; j < 4; ++j) {
            const int q = w * 4 + j;
            const int r = q * 8 + srow;
            gl_lds16(A  + (size_t)(o0 + r) * KDIM + c0 + sslot * 8, As + q * 512);
            gl_lds16(Bz + (size_t)(p0 + r) * KDIM + c0 + sslot * 8, Bs + q * 512);
        }
    };

    f32x4 acc[4][4];
    #pragma unroll
    for (int m = 0; m < 4; ++m)
        #pragma unroll
        for (int n = 0; n < 4; ++n)
            acc[m][n] = (f32x4){0.f, 0.f, 0.f, 0.f};

    stage(0);
    #pragma unroll
    for (int kt = 0; kt < KDIM / BK; ++kt) {
        __syncthreads();
        #pragma unroll
        for (int h = 0; h < 2; ++h) {
            bf16x8 af[4], bfr[4];
            #pragma unroll
            for (int m = 0; m < 4; ++m) {
                const int r  = wm * 64 + m * 16 + (lane & 15);
                const int sl = ((h << 2) | (lane >> 4)) ^ (r & 7);
                af[m] = *reinterpret_cast<const bf16x8*>(As + r * BK + sl * 8);
            }
            #pragma unroll
            for (int n = 0; n < 4; ++n) {
                const int r  = wn * 64 + n * 16 + (lane & 15);
                const int sl = ((h << 2) | (lane >> 4)) ^ (r & 7);
                bfr[n] = *reinterpret_cast<const bf16x8*>(Bs + r * BK + sl * 8);
            }
            #pragma unroll
            for (int m = 0; m < 4; ++m)
                #pragma unroll
                for (int n = 0; n < 4; ++n)
                    acc[m][n] = __builtin_amdgcn_mfma_f32_16x16x32_bf16(
                        af[m], bfr[n], acc[m][n], 0, 0, 0);
        }
        if (kt + 1 < KDIM / BK) {
            __syncthreads();
            stage((kt + 1) * BK);
        }
    }

    const int g = lane >> 4, ln15 = lane & 15;
    if (OUT_MODE == 1) {
        float* Yz = (float*)Y + (size_t)blockIdx.z * y_zs;
        #pragma unroll
        for (int m = 0; m < 4; ++m) {
            const int ow = o0 + wm * 64 + m * 16 + g * 4;
            #pragma unroll
            for (int n = 0; n < 4; ++n) {
                const int pc = p0 + wn * 64 + n * 16 + ln15;
                #pragma unroll
                for (int j = 0; j < 4; ++j)
                    Yz[(size_t)(ow + j) * PDIM + pc] = acc[m][n][j];
            }
        }
    } else {
        // QKVH: [(z*4+head)][p][192], qkv block of 64 within 192
        u16* Yz = (u16*)Y;
        const int z = blockIdx.z;
        #pragma unroll
        for (int m = 0; m < 4; ++m) {
            const int ow   = o0 + wm * 64 + m * 16 + g * 4;
            const int qkv  = ow >> 8;
            const int head = (ow >> 6) & 3;
            const int d    = ow & 63;
            u16* hbase = Yz + ((size_t)(z * NHEADS + head) * HWSZ) * 192
                            + qkv * 64 + d;
            #pragma unroll
            for (int n = 0; n < 4; ++n) {
                const int pc = p0 + wn * 64 + n * 16 + ln15;
                ushort4 st;
                st.x = f2bf(acc[m][n][0]);
                st.y = f2bf(acc[m][n][1]);
                st.z = f2bf(acc[m][n][2]);
                st.w = f2bf(acc[m][n][3]);
                *reinterpret_cast<ushort4*>(hbase + (size_t)pc * 192) = st;
            }
        }
    }
}

// ---------------------------------------------------------------------------
// Dilated neighborhood attention on QKVH [(z*4+head)][p][q64|k64|v64] bf16.
// 2 threads per position: lane pair (2i, 2i+1) splits d into halves of 32.
// Scores combined via __shfl_xor(.,1); softmax redundant per pair; each
// thread does PV for its 32 channels. Writes YT [z][p][256].
// Rate r = hi+1. OOB: score exactly 0 in softmax, zero v contribution.
// ---------------------------------------------------------------------------
__global__ __launch_bounds__(256) void attn3(
    const u16* __restrict__ QKVH, u16* __restrict__ YT)
{
    const int hi  = blockIdx.y;
    const int tid = threadIdx.x;
    const int p   = blockIdx.x * 128 + (tid >> 1);
    const int half = tid & 1;
    const int yy = p >> 7;
    const int xx = p & 127;
    const int r  = hi + 1;

    const u16* base = QKVH +
        ((size_t)(blockIdx.z * NHEADS + hi) * HWSZ) * 192;

    // q half (32 channels) -> fp32 regs
    const uint4* qp = reinterpret_cast<const uint4*>(
        base + (size_t)p * 192 + half * 32);
    float qf[32];
    #pragma unroll
    for (int c4 = 0; c4 < 4; ++c4) {
        const uint4 t = qp[c4];
        const unsigned wv[4] = {t.x, t.y, t.z, t.w};
        #pragma unroll
        for (int d = 0; d < 4; ++d) {
            qf[c4 * 8 + d * 2 + 0] = __uint_as_float(wv[d] << 16);
            qf[c4 * 8 + d * 2 + 1] = __uint_as_float(wv[d] & 0xffff0000u);
        }
    }

    int   offs[9];
    float valid[9];
    #pragma unroll
    for (int n = 0; n < 9; ++n) {
        const int dy = (n / 3 - 1) * r;
        const int dx = (n % 3 - 1) * r;
        const int y2 = yy + dy, x2 = xx + dx;
        const bool ok = (y2 >= 0) && (y2 < HH) && (x2 >= 0) && (x2 < WW);
        valid[n] = ok ? 1.f : 0.f;
        const int y2c = min(max(y2, 0), HH - 1);
        const int x2c = min(max(x2, 0), WW - 1);
        offs[n] = y2c * WW + x2c;
    }

    // Half dot-products, then pair-combine
    float sc[9];
    #pragma unroll
    for (int n = 0; n < 9; ++n) {
        const uint4* kp = reinterpret_cast<const uint4*>(
            base + (size_t)offs[n] * 192 + 64 + half * 32);
        float s = 0.f;
        #pragma unroll
        for (int c4 = 0; c4 < 4; ++c4) {
            const uint4 t = kp[c4];
            const unsigned wv[4] = {t.x, t.y, t.z, t.w};
            #pragma unroll
            for (int d = 0; d < 4; ++d) {
                s += qf[c4 * 8 + d * 2 + 0] * __uint_as_float(wv[d] << 16);
                s += qf[c4 * 8 + d * 2 + 1] * __uint_as_float(wv[d] & 0xffff0000u);
            }
        }
        sc[n] = s;
    }
    #pragma unroll
    for (int n = 0; n < 9; ++n) {
        sc[n] += __shfl_xor(sc[n], 1);
        sc[n] *= valid[n];
    }

    float m = sc[0];
    #pragma unroll
    for (int n = 1; n < 9; ++n) m = fmaxf(m, sc[n]);
    float wgt[9], den = 0.f;
    #pragma unroll
    for (int n = 0; n < 9; ++n) { wgt[n] = __expf(sc[n] - m); den += wgt[n]; }
    const float inv = 1.f / den;
    #pragma unroll
    for (int n = 0; n < 9; ++n) wgt[n] *= inv * valid[n];

    // PV for this thread's 32 channels
    float a[32];
    #pragma unroll
    for (int d = 0; d < 32; ++d) a[d] = 0.f;
    #pragma unroll
    for (int n = 0; n < 9; ++n) {
        const uint4* vp = reinterpret_cast<const uint4*>(
            base + (size_t)offs[n] * 192 + 128 + half * 32);
        const float wn_ = wgt[n];
        #pragma unroll
        for (int c4 = 0; c4 < 4; ++c4) {
            const uint4 t = vp[c4];
            const unsigned wv[4] = {t.x, t.y, t.z, t.w};
            #pragma unroll
            for (int d = 0; d < 4; ++d) {
                a[c4 * 8 + d * 2 + 0] += wn_ * __uint_as_float(wv[d] << 16);
                a[c4 * 8 + d * 2 + 1] += wn_ * __uint_as_float(wv[d] & 0xffff0000u);
            }
        }
    }

    u16* outp = YT + ((size_t)blockIdx.z * HWSZ + p) * CCH
                   + hi * DHEAD + half * 32;
    #pragma unroll
    for (int c4 = 0; c4 < 4; ++c4) {
        uint4 st;
        st.x = pack2(a[c4 * 8 + 0], a[c4 * 8 + 1]);
        st.y = pack2(a[c4 * 8 + 2], a[c4 * 8 + 3]);
        st.z = pack2(a[c4 * 8 + 4], a[c4 * 8 + 5]);
        st.w = pack2(a[c4 * 8 + 6], a[c4 * 8 + 7]);
        *reinterpret_cast<uint4*>(outp + c4 * 8) = st;
    }
}

// ---------------------------------------------------------------------------
// BN stage 1: partial (sum, sumsq) per (channel, chunk). Deterministic.
// ---------------------------------------------------------------------------
__global__ __launch_bounds__(256) void bn_partial(
    const float* __restrict__ y, float* __restrict__ part)
{
    const int c = blockIdx.x;
    const int chunk = blockIdx.y;
    const int tid = threadIdx.x;
    float s = 0.f, s2 = 0.f;
    for (int b = 0; b < BATCH; ++b) {
        const float4* pc = reinterpret_cast<const float4*>(
            y + ((size_t)b * CCH + c) * HWSZ + chunk * 2048);
        for (int i = tid; i < 512; i += 256) {
            const float4 v = pc[i];
            s  += v.x + v.y + v.z + v.w;
            s2 += v.x * v.x + v.y * v.y + v.z * v.z + v.w * v.w;
        }
    }
    __shared__ float sh0[256], sh1[256];
    sh0[tid] = s; sh1[tid] = s2;
    __syncthreads();
    for (int st = 128; st > 0; st >>= 1) {
        if (tid < st) { sh0[tid] += sh0[tid + st]; sh1[tid] += sh1[tid + st]; }
        __syncthreads();
    }
    if (tid == 0) {
        part[(c * 8 + chunk) * 2 + 0] = sh0[0];
        part[(c * 8 + chunk) * 2 + 1] = sh1[0];
    }
}

__global__ __launch_bounds__(256) void bn_final(
    const float* __restrict__ part, float* __restrict__ stats)
{
    const int c = threadIdx.x;
    float s = 0.f, s2 = 0.f;
    #pragma unroll
    for (int j = 0; j < 8; ++j) {
        s  += part[(c * 8 + j) * 2 + 0];
        s2 += part[(c * 8 + j) * 2 + 1];
    }
    const float N = (float)(BATCH * HWSZ);
    const float mean = s / N;
    const float var  = s2 / N - mean * mean;
    stats[c]       = mean;
    stats[CCH + c] = rsqrtf(var + 1e-5f);
}

// ---------------------------------------------------------------------------
// In-place epilogue: y = x + silu( (y - mean) * invstd * gamma + beta )
// ---------------------------------------------------------------------------
__global__ __launch_bounds__(256) void bn_silu_res(
    float* __restrict__ y, const float* __restrict__ x,
    const float* __restrict__ stats, const float* __restrict__ gamma,
    const float* __restrict__ beta)
{
    const size_t i = ((size_t)blockIdx.x * 256 + threadIdx.x) * 4;
    const int c = (int)((i >> 14) & 255);
    const float mean = stats[c];
    const float inv  = stats[CCH + c];
    const float g = gamma[c], bt = beta[c];

    float4 yv = *reinterpret_cast<float4*>(&y[i]);
    const float4 xv = *reinterpret_cast<const float4*>(&x[i]);
    const float vin[4] = {yv.x, yv.y, yv.z, yv.w};
    const float xin[4] = {xv.x, xv.y, xv.z, xv.w};
    float vo[4];
    #pragma unroll
    for (int t = 0; t < 4; ++t) {
        const float yn = (vin[t] - mean) * inv * g + bt;
        const float sig = 1.f / (1.f + __expf(-yn));
        vo[t] = xin[t] + yn * sig;
    }
    yv.x = vo[0]; yv.y = vo[1]; yv.z = vo[2]; yv.w = vo[3];
    *reinterpret_cast<float4*>(&y[i]) = yv;
}

// ---------------------------------------------------------------------------
extern "C" void kernel_launch(void* const* d_in, const int* in_sizes, int n_in,
                              void* d_out, int out_size, void* d_ws, size_t ws_size,
                              hipStream_t stream)
{
    const float* x      = (const float*)d_in[0];
    const float* w_qkv  = (const float*)d_in[1];
    const float* w_proj = (const float*)d_in[2];
    const float* gamma  = (const float*)d_in[3];
    const float* beta   = (const float*)d_in[4];
    float* out = (float*)d_out;

    // ws layout (~101.2 MB; proven ws >= 134.2 MB):
    u16*   XT    = (u16*)d_ws;                       // [4][16384][256] bf16
    u16*   WQb   = XT + (size_t)BATCH * HWSZ * CCH;  // [768][256]
    u16*   WPb   = WQb + 768 * CCH;                  // [256][256]
    float* part  = (float*)(WPb + CCH * CCH);        // [256][8][2]
    float* stats = part + 4096;                      // [512]
    u16*   QKVH2 = (u16*)(stats + 512);              // [2*4 heads][16384][192]
    u16*   YT2   = QKVH2 + (size_t)2 * HWSZ * 768;   // [2][16384][256]

    // 1) weights -> bf16
    wconv<<<256, 256, 0, stream>>>(w_qkv, w_proj, WQb, WPb);

    // 2) x -> XT (transpose + bf16)
    transpose_x<<<dim3(HWSZ / 32, CCH / 32, BATCH), 256, 0, stream>>>(x, XT);

    // 3) per batch-pair: QKV GEMM -> attention -> proj GEMM
    for (int pair = 0; pair < 2; ++pair) {
        const u16* Bx = XT + (size_t)pair * 2 * HWSZ * CCH;
        gemm_mfma<0><<<dim3(PDIM / 128, 768 / 128, 2), 256, 0, stream>>>(
            WQb, Bx, QKVH2, (long long)HWSZ * CCH, 0);

        attn3<<<dim3(HWSZ / 128, NHEADS, 2), 256, 0, stream>>>(QKVH2, YT2);

        gemm_mfma<1><<<dim3(PDIM / 128, CCH / 128, 2), 256, 0, stream>>>(
            WPb, YT2, out + (size_t)pair * 2 * CCH * HWSZ,
            (long long)HWSZ * CCH, (long long)CCH * HWSZ);
    }

    // 4) BN stats (two-stage, deterministic)
    bn_partial<<<dim3(CCH, 8), 256, 0, stream>>>(out, part);
    bn_final<<<1, 256, 0, stream>>>(part, stats);

    // 5) BN + SiLU + residual (in place on d_out)
    bn_silu_res<<<(unsigned)((size_t)BATCH * CCH * HWSZ / 4 / 256), 256, 0, stream>>>(
        out, x, stats, gamma, beta);
}

// Round 6
// 162.813 us; speedup vs baseline: 6.9350x; 1.1799x over previous
//
#include <hip/hip_runtime.h>
#include <hip/hip_bf16.h>

#define BATCH 4
#define CCH   256
#define HH    128
#define WW    128
#define HWSZ  (HH * WW)         // 16384
#define NHEADS 4
#define DHEAD 64
#define KDIM  256
#define PDIM  16384

typedef unsigned short u16;
typedef short bf16x8 __attribute__((ext_vector_type(8)));
typedef float f32x4  __attribute__((ext_vector_type(4)));

__device__ __forceinline__ float bf2f(u16 u) {
    return __uint_as_float(((unsigned)u) << 16);
}
__device__ __forceinline__ u16 f2bf(float f) {
    unsigned u = __float_as_uint(f);
    unsigned r = (u + 0x7fffu + ((u >> 16) & 1u)) >> 16;
    return (u16)r;
}
__device__ __forceinline__ unsigned pack2(float a, float b) {
    return (unsigned)f2bf(a) | ((unsigned)f2bf(b) << 16);
}
__device__ __forceinline__ void gl_lds16(const u16* g, u16* l) {
    __builtin_amdgcn_global_load_lds(
        (const __attribute__((address_space(1))) void*)g,
        (__attribute__((address_space(3))) void*)l, 16, 0, 0);
}

// ---------------------------------------------------------------------------
// Weight fp32 -> bf16 conversion (both weights in one kernel).
// ---------------------------------------------------------------------------
__global__ __launch_bounds__(256) void wconv(
    const float* __restrict__ wq, const float* __restrict__ wp,
    u16* __restrict__ wqb, u16* __restrict__ wpb)
{
    const int i = (blockIdx.x * 256 + threadIdx.x) * 4;   // < 262144
    const float4 v = (i < 196608)
        ? *reinterpret_cast<const float4*>(&wq[i])
        : *reinterpret_cast<const float4*>(&wp[i - 196608]);
    ushort4 o;
    o.x = f2bf(v.x); o.y = f2bf(v.y); o.z = f2bf(v.z); o.w = f2bf(v.w);
    if (i < 196608) *reinterpret_cast<ushort4*>(&wqb[i]) = o;
    else            *reinterpret_cast<ushort4*>(&wpb[i - 196608]) = o;
}

// ---------------------------------------------------------------------------
// Transpose + convert: x [b][c][p] fp32 -> XT [b][p][c] bf16. 32x32 tiles.
// ---------------------------------------------------------------------------
__global__ __launch_bounds__(256) void transpose_x(
    const float* __restrict__ x, u16* __restrict__ XT)
{
    __shared__ float t[32][33];
    const int b  = blockIdx.z;
    const int c0 = blockIdx.y * 32;
    const int p0 = blockIdx.x * 32;
    const int tid = threadIdx.x;

    #pragma unroll
    for (int it = 0; it < 4; ++it) {
        const int r = it * 8 + (tid >> 5);
        const int col = tid & 31;
        t[r][col] = x[((size_t)b * CCH + c0 + r) * HWSZ + p0 + col];
    }
    __syncthreads();
    #pragma unroll
    for (int it = 0; it < 2; ++it) {
        const int prow = it * 16 + (tid >> 4);
        const int cpair = (tid & 15) * 2;
        const float v0 = t[cpair][prow];
        const float v1 = t[cpair + 1][prow];
        ushort2 o; o.x = f2bf(v0); o.y = f2bf(v1);
        *reinterpret_cast<ushort2*>(
            &XT[((size_t)b * HWSZ + p0 + prow) * CCH + c0 + cpair]) = o;
    }
}

// ---------------------------------------------------------------------------
// MFMA GEMM: D[o][p] = sum_k A[o][k] * B[p][k]   (both bf16, k-contiguous)
// K=256, BK=64, tile 128x128, 4 waves (2x2), 16x mfma_f32_16x16x32_bf16.
// LDS rows 128B, XOR swizzle slot^=(row&7), staged via global_load_lds w16
// with pre-swizzled global source (linear LDS dest).
// OUT_MODE=0: bf16 QKVH layout [(z*4+head)][p][q64|k64|v64] (O=768).
// OUT_MODE=1: bf16 YP [batch0+z][o][p] + fused BN partial (sum,sumsq) per
//             (channel, 64-px block) written to part (deterministic).
// ---------------------------------------------------------------------------
template <int OUT_MODE>
__global__ __launch_bounds__(256) void gemm_mfma(
    const u16* __restrict__ A, const u16* __restrict__ B,
    void* __restrict__ Y, long long b_zs,
    float* __restrict__ part, int batch0)
{
    constexpr int BK = 64;
    __shared__ u16 As[128 * BK];
    __shared__ u16 Bs[128 * BK];

    const int tid  = threadIdx.x;
    const int lane = tid & 63;
    const int w    = tid >> 6;
    const int wm   = w >> 1, wn = w & 1;
    const int o0   = blockIdx.y * 128;
    const int p0   = blockIdx.x * 128;
    const u16* Bz  = B + (size_t)blockIdx.z * b_zs;

    const int srow  = lane >> 3;
    const int sslot = (lane & 7) ^ srow;

    auto stage = [&](int c0) {
        #pragma unroll
        for (int j = 0; j < 4; ++j) {
            const int q = w * 4 + j;
            const int r = q * 8 + srow;
            gl_lds16(A  + (size_t)(o0 + r) * KDIM + c0 + sslot * 8, As + q * 512);
            gl_lds16(Bz + (size_t)(p0 + r) * KDIM + c0 + sslot * 8, Bs + q * 512);
        }
    };

    f32x4 acc[4][4];
    #pragma unroll
    for (int m = 0; m < 4; ++m)
        #pragma unroll
        for (int n = 0; n < 4; ++n)
            acc[m][n] = (f32x4){0.f, 0.f, 0.f, 0.f};

    stage(0);
    #pragma unroll
    for (int kt = 0; kt < KDIM / BK; ++kt) {
        __syncthreads();
        #pragma unroll
        for (int h = 0; h < 2; ++h) {
            bf16x8 af[4], bfr[4];
            #pragma unroll
            for (int m = 0; m < 4; ++m) {
                const int r  = wm * 64 + m * 16 + (lane & 15);
                const int sl = ((h << 2) | (lane >> 4)) ^ (r & 7);
                af[m] = *reinterpret_cast<const bf16x8*>(As + r * BK + sl * 8);
            }
            #pragma unroll
            for (int n = 0; n < 4; ++n) {
                const int r  = wn * 64 + n * 16 + (lane & 15);
                const int sl = ((h << 2) | (lane >> 4)) ^ (r & 7);
                bfr[n] = *reinterpret_cast<const bf16x8*>(Bs + r * BK + sl * 8);
            }
            #pragma unroll
            for (int m = 0; m < 4; ++m)
                #pragma unroll
                for (int n = 0; n < 4; ++n)
                    acc[m][n] = __builtin_amdgcn_mfma_f32_16x16x32_bf16(
                        af[m], bfr[n], acc[m][n], 0, 0, 0);
        }
        if (kt + 1 < KDIM / BK) {
            __syncthreads();
            stage((kt + 1) * BK);
        }
    }

    const int g = lane >> 4, ln15 = lane & 15;
    if (OUT_MODE == 1) {
        // bf16 YP [batch][o][p] + fused BN partials
        const int batch = batch0 + blockIdx.z;
        u16* Yz = (u16*)Y + (size_t)batch * CCH * HWSZ;
        float s[4][4], q2[4][4];
        #pragma unroll
        for (int m = 0; m < 4; ++m) {
            const int ow = o0 + wm * 64 + m * 16 + g * 4;
            #pragma unroll
            for (int j = 0; j < 4; ++j) { s[m][j] = 0.f; q2[m][j] = 0.f; }
            #pragma unroll
            for (int n = 0; n < 4; ++n) {
                const int pc = p0 + wn * 64 + n * 16 + ln15;
                #pragma unroll
                for (int j = 0; j < 4; ++j) {
                    const float v = acc[m][n][j];
                    Yz[(size_t)(ow + j) * PDIM + pc] = f2bf(v);
                    s[m][j]  += v;
                    q2[m][j] += v * v;
                }
            }
        }
        // reduce over the 16 px-lanes (bits 0..3 of lane)
        #pragma unroll
        for (int mask = 1; mask <= 8; mask <<= 1) {
            #pragma unroll
            for (int m = 0; m < 4; ++m)
                #pragma unroll
                for (int j = 0; j < 4; ++j) {
                    s[m][j]  += __shfl_xor(s[m][j],  mask);
                    q2[m][j] += __shfl_xor(q2[m][j], mask);
                }
        }
        if (ln15 == 0) {
            const int pxblk = batch * 256 + blockIdx.x * 2 + wn;  // 64-px block
            #pragma unroll
            for (int m = 0; m < 4; ++m) {
                const int ow = o0 + wm * 64 + m * 16 + g * 4;
                #pragma unroll
                for (int j = 0; j < 4; ++j) {
                    const size_t idx = ((size_t)(ow + j) * 1024 + pxblk) * 2;
                    part[idx]     = s[m][j];
                    part[idx + 1] = q2[m][j];
                }
            }
        }
    } else {
        // QKVH: [(z*4+head)][p][192], qkv block of 64 within 192
        u16* Yz = (u16*)Y;
        const int z = blockIdx.z;
        #pragma unroll
        for (int m = 0; m < 4; ++m) {
            const int ow   = o0 + wm * 64 + m * 16 + g * 4;
            const int qkv  = ow >> 8;
            const int head = (ow >> 6) & 3;
            const int d    = ow & 63;
            u16* hbase = Yz + ((size_t)(z * NHEADS + head) * HWSZ) * 192
                            + qkv * 64 + d;
            #pragma unroll
            for (int n = 0; n < 4; ++n) {
                const int pc = p0 + wn * 64 + n * 16 + ln15;
                ushort4 st;
                st.x = f2bf(acc[m][n][0]);
                st.y = f2bf(acc[m][n][1]);
                st.z = f2bf(acc[m][n][2]);
                st.w = f2bf(acc[m][n][3]);
                *reinterpret_cast<ushort4*>(hbase + (size_t)pc * 192) = st;
            }
        }
    }
}

// ---------------------------------------------------------------------------
// Dilated neighborhood attention on QKVH [(z*4+head)][p][q64|k64|v64] bf16.
// 4 threads per position (16 channels each); scores combined via
// __shfl_xor(.,1) and (.,2); softmax redundant per quad; PV per 16 channels.
// XCD-aware blockIdx.x swizzle: each XCD gets a contiguous 2048-px band.
// Rate r = hi+1. OOB: score exactly 0 in softmax, zero v contribution.
// ---------------------------------------------------------------------------
__global__ __launch_bounds__(256) void attn4(
    const u16* __restrict__ QKVH, u16* __restrict__ YT)
{
    const int hi  = blockIdx.y;
    const int tid = threadIdx.x;
    const int bxr = blockIdx.x;                       // 0..255
    const int bx  = (bxr & 7) * 32 + (bxr >> 3);      // XCD-contiguous bands
    const int p   = bx * 64 + (tid >> 2);
    const int quarter = tid & 3;
    const int yy = p >> 7;
    const int xx = p & 127;
    const int r  = hi + 1;

    const u16* base = QKVH +
        ((size_t)(blockIdx.z * NHEADS + hi) * HWSZ) * 192;

    // q quarter (16 channels) -> fp32 regs
    const uint4* qp = reinterpret_cast<const uint4*>(
        base + (size_t)p * 192 + quarter * 16);
    float qf[16];
    #pragma unroll
    for (int c4 = 0; c4 < 2; ++c4) {
        const uint4 t = qp[c4];
        const unsigned wv[4] = {t.x, t.y, t.z, t.w};
        #pragma unroll
        for (int d = 0; d < 4; ++d) {
            qf[c4 * 8 + d * 2 + 0] = __uint_as_float(wv[d] << 16);
            qf[c4 * 8 + d * 2 + 1] = __uint_as_float(wv[d] & 0xffff0000u);
        }
    }

    int   offs[9];
    float valid[9];
    #pragma unroll
    for (int n = 0; n < 9; ++n) {
        const int dy = (n / 3 - 1) * r;
        const int dx = (n % 3 - 1) * r;
        const int y2 = yy + dy, x2 = xx + dx;
        const bool ok = (y2 >= 0) && (y2 < HH) && (x2 >= 0) && (x2 < WW);
        valid[n] = ok ? 1.f : 0.f;
        const int y2c = min(max(y2, 0), HH - 1);
        const int x2c = min(max(x2, 0), WW - 1);
        offs[n] = y2c * WW + x2c;
    }

    // Quarter dot-products, then quad-combine
    float sc[9];
    #pragma unroll
    for (int n = 0; n < 9; ++n) {
        const uint4* kp = reinterpret_cast<const uint4*>(
            base + (size_t)offs[n] * 192 + 64 + quarter * 16);
        float s = 0.f;
        #pragma unroll
        for (int c4 = 0; c4 < 2; ++c4) {
            const uint4 t = kp[c4];
            const unsigned wv[4] = {t.x, t.y, t.z, t.w};
            #pragma unroll
            for (int d = 0; d < 4; ++d) {
                s += qf[c4 * 8 + d * 2 + 0] * __uint_as_float(wv[d] << 16);
                s += qf[c4 * 8 + d * 2 + 1] * __uint_as_float(wv[d] & 0xffff0000u);
            }
        }
        sc[n] = s;
    }
    #pragma unroll
    for (int n = 0; n < 9; ++n) {
        sc[n] += __shfl_xor(sc[n], 1);
        sc[n] += __shfl_xor(sc[n], 2);
        sc[n] *= valid[n];
    }

    float m = sc[0];
    #pragma unroll
    for (int n = 1; n < 9; ++n) m = fmaxf(m, sc[n]);
    float wgt[9], den = 0.f;
    #pragma unroll
    for (int n = 0; n < 9; ++n) { wgt[n] = __expf(sc[n] - m); den += wgt[n]; }
    const float inv = 1.f / den;
    #pragma unroll
    for (int n = 0; n < 9; ++n) wgt[n] *= inv * valid[n];

    // PV for this thread's 16 channels
    float a[16];
    #pragma unroll
    for (int d = 0; d < 16; ++d) a[d] = 0.f;
    #pragma unroll
    for (int n = 0; n < 9; ++n) {
        const uint4* vp = reinterpret_cast<const uint4*>(
            base + (size_t)offs[n] * 192 + 128 + quarter * 16);
        const float wn_ = wgt[n];
        #pragma unroll
        for (int c4 = 0; c4 < 2; ++c4) {
            const uint4 t = vp[c4];
            const unsigned wv[4] = {t.x, t.y, t.z, t.w};
            #pragma unroll
            for (int d = 0; d < 4; ++d) {
                a[c4 * 8 + d * 2 + 0] += wn_ * __uint_as_float(wv[d] << 16);
                a[c4 * 8 + d * 2 + 1] += wn_ * __uint_as_float(wv[d] & 0xffff0000u);
            }
        }
    }

    u16* outp = YT + ((size_t)blockIdx.z * HWSZ + p) * CCH
                   + hi * DHEAD + quarter * 16;
    #pragma unroll
    for (int c4 = 0; c4 < 2; ++c4) {
        uint4 st;
        st.x = pack2(a[c4 * 8 + 0], a[c4 * 8 + 1]);
        st.y = pack2(a[c4 * 8 + 2], a[c4 * 8 + 3]);
        st.z = pack2(a[c4 * 8 + 4], a[c4 * 8 + 5]);
        st.w = pack2(a[c4 * 8 + 6], a[c4 * 8 + 7]);
        *reinterpret_cast<uint4*>(outp + c4 * 8) = st;
    }
}

// ---------------------------------------------------------------------------
// BN final: per channel, reduce 1024 (sum,sumsq) partials. Deterministic.
// ---------------------------------------------------------------------------
__global__ __launch_bounds__(256) void bn_final(
    const float* __restrict__ part, float* __restrict__ stats)
{
    const int c = blockIdx.x;
    const int tid = threadIdx.x;
    float s = 0.f, q = 0.f;
    #pragma unroll
    for (int it = 0; it < 4; ++it) {
        const int i = tid + it * 256;
        s += part[((size_t)c * 1024 + i) * 2 + 0];
        q += part[((size_t)c * 1024 + i) * 2 + 1];
    }
    __shared__ float sh0[256], sh1[256];
    sh0[tid] = s; sh1[tid] = q;
    __syncthreads();
    for (int st = 128; st > 0; st >>= 1) {
        if (tid < st) { sh0[tid] += sh0[tid + st]; sh1[tid] += sh1[tid + st]; }
        __syncthreads();
    }
    if (tid == 0) {
        const float N = (float)(BATCH * HWSZ);
        const float mean = sh0[0] / N;
        const float var  = sh1[0] / N - mean * mean;
        stats[c]       = mean;
        stats[CCH + c] = rsqrtf(var + 1e-5f);
    }
}

// ---------------------------------------------------------------------------
// Epilogue: out = x + silu( (yp - mean) * invstd * gamma + beta ), yp bf16.
// 8 elements per thread.
// ---------------------------------------------------------------------------
__global__ __launch_bounds__(256) void bn_silu_res(
    const u16* __restrict__ yp, const float* __restrict__ x,
    const float* __restrict__ stats, const float* __restrict__ gamma,
    const float* __restrict__ beta, float* __restrict__ out)
{
    const size_t i = ((size_t)blockIdx.x * 256 + threadIdx.x) * 8;
    const int c = (int)((i >> 14) & 255);
    const float mean = stats[c];
    const float inv  = stats[CCH + c];
    const float g = gamma[c], bt = beta[c];

    const uint4 yv = *reinterpret_cast<const uint4*>(&yp[i]);
    const unsigned wv[4] = {yv.x, yv.y, yv.z, yv.w};
    float vo[8];
    #pragma unroll
    for (int d = 0; d < 4; ++d) {
        const float y0 = __uint_as_float(wv[d] << 16);
        const float y1 = __uint_as_float(wv[d] & 0xffff0000u);
        const float yn0 = (y0 - mean) * inv * g + bt;
        const float yn1 = (y1 - mean) * inv * g + bt;
        vo[d * 2 + 0] = yn0 / (1.f + __expf(-yn0));
        vo[d * 2 + 1] = yn1 / (1.f + __expf(-yn1));
    }
    const float4 x0 = *reinterpret_cast<const float4*>(&x[i]);
    const float4 x1 = *reinterpret_cast<const float4*>(&x[i + 4]);
    float4 o0, o1;
    o0.x = x0.x + vo[0]; o0.y = x0.y + vo[1];
    o0.z = x0.z + vo[2]; o0.w = x0.w + vo[3];
    o1.x = x1.x + vo[4]; o1.y = x1.y + vo[5];
    o1.z = x1.z + vo[6]; o1.w = x1.w + vo[7];
    *reinterpret_cast<float4*>(&out[i])     = o0;
    *reinterpret_cast<float4*>(&out[i + 4]) = o1;
}

// ---------------------------------------------------------------------------
extern "C" void kernel_launch(void* const* d_in, const int* in_sizes, int n_in,
                              void* d_out, int out_size, void* d_ws, size_t ws_size,
                              hipStream_t stream)
{
    const float* x      = (const float*)d_in[0];
    const float* w_qkv  = (const float*)d_in[1];
    const float* w_proj = (const float*)d_in[2];
    const float* gamma  = (const float*)d_in[3];
    const float* beta   = (const float*)d_in[4];
    float* out = (float*)d_out;

    // ws layout (~103 MB; proven ws >= 134.2 MB):
    //   XT [4][16384][256] bf16 (33.5 MB) -- YP aliases it (per-pair halves
    //   are dead by the time gemm2 of that pair writes them)
    u16*   XT    = (u16*)d_ws;
    u16*   YP    = XT;                               // alias (see above)
    u16*   WQb   = XT + (size_t)BATCH * HWSZ * CCH;  // [768][256]
    u16*   WPb   = WQb + 768 * CCH;                  // [256][256]
    float* part  = (float*)(WPb + CCH * CCH);        // [256][1024][2] = 2 MB
    float* stats = part + (size_t)CCH * 1024 * 2;    // [512]
    u16*   QKVH2 = (u16*)(stats + 512);              // [2*4 heads][16384][192]
    u16*   YT2   = QKVH2 + (size_t)2 * HWSZ * 768;   // [2][16384][256]

    // 1) weights -> bf16
    wconv<<<256, 256, 0, stream>>>(w_qkv, w_proj, WQb, WPb);

    // 2) x -> XT (transpose + bf16)
    transpose_x<<<dim3(HWSZ / 32, CCH / 32, BATCH), 256, 0, stream>>>(x, XT);

    // 3) per batch-pair: QKV GEMM -> attention -> proj GEMM (+BN partials)
    for (int pair = 0; pair < 2; ++pair) {
        const u16* Bx = XT + (size_t)pair * 2 * HWSZ * CCH;
        gemm_mfma<0><<<dim3(PDIM / 128, 768 / 128, 2), 256, 0, stream>>>(
            WQb, Bx, QKVH2, (long long)HWSZ * CCH, nullptr, 0);

        attn4<<<dim3(HWSZ / 64, NHEADS, 2), 256, 0, stream>>>(QKVH2, YT2);

        gemm_mfma<1><<<dim3(PDIM / 128, CCH / 128, 2), 256, 0, stream>>>(
            WPb, YT2, YP, (long long)HWSZ * CCH, part, pair * 2);
    }

    // 4) BN stats from fused partials
    bn_final<<<CCH, 256, 0, stream>>>(part, stats);

    // 5) BN + SiLU + residual: out = x + silu(bn(YP))
    bn_silu_res<<<(unsigned)((size_t)BATCH * CCH * HWSZ / 8 / 256), 256, 0, stream>>>(
        YP, x, stats, gamma, beta, out);
}